// Round 1
// baseline (155.811 us; speedup 1.0000x reference)
//
#include <hip/hip_runtime.h>

#define NPIX 4096
#define FEAT 128
#define LAT 64
#define BS 64
#define NSTEPS 6

// flat f32 output offsets (log_m_k, log_s_k, c_f, delta, seeds)
#define OFF_LOGM  0u
#define OFF_LOGS  1835008u
#define OFF_CF    3670016u
#define OFF_DELTA 20447232u
#define OFF_SEEDS 20971520u

__device__ __forceinline__ void amax_comb(float& bv, int& bi, float v, int i) {
    if (v > bv || (v == bv && i < bi)) { bv = v; bi = i; }
}

// K1: 1x1 conv GEMM. block = 256 thr = 4 waves; wave og handles outputs og*16..+15,
// each lane handles 4 consecutive pixels; block covers 256 pixels of one batch.
// grid = 64 batches * 16 tiles = 1024 blocks.
__global__ __launch_bounds__(256, 2) void conv_kernel(
    const float* __restrict__ x, const float* __restrict__ rand_pixel,
    const float* __restrict__ w, const float* __restrict__ bias,
    const float* __restrict__ gate_p, float* __restrict__ out,
    float* __restrict__ pval, int* __restrict__ pidx)
{
    __shared__ float wT[FEAT][68];   // transposed weights, padded stride (16B aligned rows)

    const int tid  = threadIdx.x;
    const int b    = blockIdx.x >> 4;
    const int tile = blockIdx.x & 15;
    const int p0   = tile * 256;
    const int lane = tid & 63;
    const int og   = tid >> 6;

    // stage weights transposed: wT[f][o] = w[o*128+f]
    #pragma unroll
    for (int k = 0; k < 32; ++k) {
        int idx = k * 256 + tid;
        wT[idx & 127][idx >> 7] = w[idx];
    }
    __syncthreads();

    const float gate = gate_p[0];

    float4 acc[16];
    #pragma unroll
    for (int i = 0; i < 16; ++i) acc[i] = make_float4(0.f, 0.f, 0.f, 0.f);

    const float* xb = x + (size_t)b * FEAT * NPIX + p0 + lane * 4;

    #pragma unroll 2
    for (int f = 0; f < FEAT; ++f) {
        float4 xv = *(const float4*)(xb + (size_t)f * NPIX);
        const float* wrow = &wT[f][og * 16];
        #pragma unroll
        for (int oi = 0; oi < 16; oi += 4) {
            float4 wv = *(const float4*)(wrow + oi);
            acc[oi+0].x = fmaf(wv.x, xv.x, acc[oi+0].x);
            acc[oi+0].y = fmaf(wv.x, xv.y, acc[oi+0].y);
            acc[oi+0].z = fmaf(wv.x, xv.z, acc[oi+0].z);
            acc[oi+0].w = fmaf(wv.x, xv.w, acc[oi+0].w);
            acc[oi+1].x = fmaf(wv.y, xv.x, acc[oi+1].x);
            acc[oi+1].y = fmaf(wv.y, xv.y, acc[oi+1].y);
            acc[oi+1].z = fmaf(wv.y, xv.z, acc[oi+1].z);
            acc[oi+1].w = fmaf(wv.y, xv.w, acc[oi+1].w);
            acc[oi+2].x = fmaf(wv.z, xv.x, acc[oi+2].x);
            acc[oi+2].y = fmaf(wv.z, xv.y, acc[oi+2].y);
            acc[oi+2].z = fmaf(wv.z, xv.z, acc[oi+2].z);
            acc[oi+2].w = fmaf(wv.z, xv.w, acc[oi+2].w);
            acc[oi+3].x = fmaf(wv.w, xv.x, acc[oi+3].x);
            acc[oi+3].y = fmaf(wv.w, xv.y, acc[oi+3].y);
            acc[oi+3].z = fmaf(wv.w, xv.z, acc[oi+3].z);
            acc[oi+3].w = fmaf(wv.w, xv.w, acc[oi+3].w);
        }
    }

    const int pbase = p0 + lane * 4;
    float* cf = out + OFF_CF + (size_t)b * LAT * NPIX;

    #pragma unroll
    for (int oi = 0; oi < 16; ++oi) {
        int o = og * 16 + oi;
        float bo = bias[o];
        float4 v;
        v.x = gate * (acc[oi].x + bo);
        v.y = gate * (acc[oi].y + bo);
        v.z = gate * (acc[oi].z + bo);
        v.w = gate * (acc[oi].w + bo);
        if (o >= 62) {
            // delta = out[:, -2:] before uv add
            float* dp = out + OFF_DELTA + ((size_t)b * 2 + (o - 62)) * NPIX + pbase;
            *(float4*)dp = v;
            if (o == 62) {
                float g1 = (float)(-1.0 + 2.0 * (double)(pbase >> 6) / 63.0);
                v.x += g1; v.y += g1; v.z += g1; v.w += g1;
            } else {
                int j = pbase & 63;
                v.x += (float)(-1.0 + 2.0 * (double)(j + 0) / 63.0);
                v.y += (float)(-1.0 + 2.0 * (double)(j + 1) / 63.0);
                v.z += (float)(-1.0 + 2.0 * (double)(j + 2) / 63.0);
                v.w += (float)(-1.0 + 2.0 * (double)(j + 3) / 63.0);
            }
        }
        *(float4*)(cf + (size_t)o * NPIX + pbase) = v;
    }

    // wave 0 extras: zero log_s_k[0], and step-0 argmax partial (probs == rand_pixel)
    if (og == 0) {
        *(float4*)(out + OFF_LOGS + (size_t)b * NPIX + pbase) = make_float4(0.f, 0.f, 0.f, 0.f);

        float4 rv = *(const float4*)(rand_pixel + (size_t)b * NPIX + pbase);
        float bv = rv.x; int bi = pbase;
        if (rv.y > bv) { bv = rv.y; bi = pbase + 1; }
        if (rv.z > bv) { bv = rv.z; bi = pbase + 2; }
        if (rv.w > bv) { bv = rv.w; bi = pbase + 3; }
        #pragma unroll
        for (int off = 32; off > 0; off >>= 1) {
            float ov = __shfl_down(bv, off, 64);
            int   oi2 = __shfl_down(bi, off, 64);
            amax_comb(bv, bi, ov, oi2);
        }
        if (lane == 0) { pval[blockIdx.x] = bv; pidx[blockIdx.x] = bi; }
    }
}

// K3: one clustering step. grid = 1024 blocks (64 batches x 16 tiles) x 256 thr;
// thread = one pixel. Merges argmax partials, gathers seed, updates log_m/log_s,
// then emits next step's argmax partials.
__global__ __launch_bounds__(256, 4) void step_kernel(
    const float* __restrict__ rand_pixel, const float* __restrict__ log_sigma_p,
    float* __restrict__ out, float* __restrict__ pval, int* __restrict__ pidx,
    int step)
{
    __shared__ float s_seed[LAT];
    __shared__ float s_rv[4];
    __shared__ int   s_ri[4];

    const int tid  = threadIdx.x;
    const int b    = blockIdx.x >> 4;
    const int tile = blockIdx.x & 15;
    const int p    = tile * 256 + tid;

    // phase A: merge the 16 partials of this batch (redundantly per block)
    float bv = -1.0f; int bi = 0;
    #pragma unroll
    for (int k = 0; k < 16; ++k) {
        float v = pval[b * 16 + k];
        int  id = pidx[b * 16 + k];
        amax_comb(bv, bi, v, id);
    }

    const float* cf = out + OFF_CF + (size_t)b * LAT * NPIX;
    if (tid < LAT) s_seed[tid] = cf[(size_t)tid * NPIX + bi];
    __syncthreads();

    if (tile == 0 && tid < LAT)
        out[OFF_SEEDS + ((size_t)step * BS + b) * LAT + tid] = s_seed[tid];

    // phase B: per-pixel distance + log-space update
    float d2 = 0.f;
    #pragma unroll 16
    for (int c = 0; c < LAT; ++c) {
        float d = cf[(size_t)c * NPIX + p] - s_seed[c];
        d2 = fmaf(d, d, d2);
    }
    float dist  = sqrtf(fminf(fmaxf(d2, 1e-10f), 1e10f));
    float sigma = expf(log_sigma_p[0]);
    float alpha = expf(-dist / sigma);
    alpha = fminf(fmaxf(alpha, 0.01f), 0.99f);

    float ls  = out[OFF_LOGS + ((size_t)step * BS + b) * NPIX + p];
    float lm  = ls + logf(alpha);
    float lsn = ls + log1pf(-alpha);

    out[OFF_LOGM + ((size_t)step * BS + b) * NPIX + p]       = lm;
    out[OFF_LOGS + ((size_t)(step + 1) * BS + b) * NPIX + p] = lsn;
    if (step == NSTEPS - 1)
        out[OFF_LOGM + ((size_t)NSTEPS * BS + b) * NPIX + p] = lsn;

    // phase C: next step's argmax partial
    if (step < NSTEPS - 1) {
        float prob = rand_pixel[(size_t)b * NPIX + p] * expf(lsn);
        int   idx  = p;
        #pragma unroll
        for (int off = 32; off > 0; off >>= 1) {
            float ov = __shfl_down(prob, off, 64);
            int   oi = __shfl_down(idx, off, 64);
            amax_comb(prob, idx, ov, oi);
        }
        int lane = tid & 63, wid = tid >> 6;
        if (lane == 0) { s_rv[wid] = prob; s_ri[wid] = idx; }
        __syncthreads();
        if (tid == 0) {
            float fb = s_rv[0]; int fi = s_ri[0];
            #pragma unroll
            for (int k = 1; k < 4; ++k) amax_comb(fb, fi, s_rv[k], s_ri[k]);
            pval[blockIdx.x] = fb; pidx[blockIdx.x] = fi;
        }
    }
}

extern "C" void kernel_launch(void* const* d_in, const int* in_sizes, int n_in,
                              void* d_out, int out_size, void* d_ws, size_t ws_size,
                              hipStream_t stream) {
    const float* x          = (const float*)d_in[0];
    const float* rand_pixel = (const float*)d_in[1];
    const float* w          = (const float*)d_in[2];
    const float* bias       = (const float*)d_in[3];
    const float* gate       = (const float*)d_in[4];
    const float* log_sigma  = (const float*)d_in[5];
    // d_in[6] = num_cl_steps (always 6 per setup_inputs)

    float* out  = (float*)d_out;
    float* pval = (float*)d_ws;
    int*   pidx = (int*)((char*)d_ws + 1024 * sizeof(float));

    conv_kernel<<<1024, 256, 0, stream>>>(x, rand_pixel, w, bias, gate, out, pval, pidx);
    for (int s = 0; s < NSTEPS; ++s)
        step_kernel<<<1024, 256, 0, stream>>>(rand_pixel, log_sigma, out, pval, pidx, s);
}